// Round 4
// baseline (215.245 us; speedup 1.0000x reference)
//
#include <hip/hip_runtime.h>
#include <hip/hip_bf16.h>
#include <stdint.h>

#define E_ 8
#define D_ 768
#define O_ 3072
#define N_ 2048   // B*S = 4*512

typedef __attribute__((ext_vector_type(8))) __bf16 bf16x8;
typedef __attribute__((ext_vector_type(4))) float f32x4;

// round-to-nearest-even fp32 -> bf16 bits
__device__ __forceinline__ unsigned short f2bf(float f) {
    union { float f; uint32_t u; } a; a.f = f;
    uint32_t u = a.u;
    uint32_t r = (u + 0x7fffu + ((u >> 16) & 1u)) >> 16;
    return (unsigned short)r;
}

__device__ __forceinline__ void async16(const void* g, void* l) {
    __builtin_amdgcn_global_load_lds(
        (const __attribute__((address_space(1))) void*)g,
        (__attribute__((address_space(3))) void*)l, 16, 0, 0);
}

// ---------------- fused prologue ----------------
// blocks [0,512):       gating (1 wave/token) + x->bf16 cast + y zeroing
// blocks [512,512+9216): Wb[e] = bf16(expert_w[e] + static_w), 8 elem/thread
__global__ __launch_bounds__(256) void prologue_kernel(
    const float* __restrict__ x, const float* __restrict__ w_gate,
    const float* __restrict__ ew, const float* __restrict__ sw,
    unsigned short* __restrict__ xb, unsigned short* __restrict__ wb,
    int* __restrict__ choice_e, float* __restrict__ choice_g,
    float* __restrict__ y)
{
    if (blockIdx.x >= 512) {
        // ---- prep_w: one uint4 (8 bf16) store per thread ----
        int i = (blockIdx.x - 512) * 256 + threadIdx.x;   // 8-elem units
        int f = i * 8;
        const int od = O_ * D_;
        int e = f / od;
        int rem = f - e * od;
        float4 a0 = *(const float4*)(ew + f);
        float4 a1 = *(const float4*)(ew + f + 4);
        float4 b0 = *(const float4*)(sw + rem);
        float4 b1 = *(const float4*)(sw + rem + 4);
        union { ushort u[8]; uint4 v; } o;
        o.u[0] = f2bf(a0.x + b0.x); o.u[1] = f2bf(a0.y + b0.y);
        o.u[2] = f2bf(a0.z + b0.z); o.u[3] = f2bf(a0.w + b0.w);
        o.u[4] = f2bf(a1.x + b1.x); o.u[5] = f2bf(a1.y + b1.y);
        o.u[6] = f2bf(a1.z + b1.z); o.u[7] = f2bf(a1.w + b1.w);
        ((uint4*)wb)[i] = o.v;
        return;
    }

    // ---- gating ----
    int wid  = threadIdx.x >> 6;
    int lane = threadIdx.x & 63;
    int n = blockIdx.x * 4 + wid;
    const float* xr = x + (size_t)n * D_;

    float acc[E_];
#pragma unroll
    for (int e = 0; e < E_; ++e) acc[e] = 0.f;

    for (int c = 0; c < D_ / 64; ++c) {
        int d = c * 64 + lane;
        float xv = xr[d];
        xb[(size_t)n * D_ + d] = f2bf(xv);          // fused cast
        const float* wg = w_gate + (size_t)d * E_;
        float4 w0 = *(const float4*)(wg);
        float4 w1 = *(const float4*)(wg + 4);
        acc[0] += xv * w0.x; acc[1] += xv * w0.y;
        acc[2] += xv * w0.z; acc[3] += xv * w0.w;
        acc[4] += xv * w1.x; acc[5] += xv * w1.y;
        acc[6] += xv * w1.z; acc[7] += xv * w1.w;
    }
#pragma unroll
    for (int e = 0; e < E_; ++e) {
        float v = acc[e];
        for (int off = 32; off > 0; off >>= 1) v += __shfl_xor(v, off, 64);
        acc[e] = v;
    }
    if (lane == 0) {
        // top-2, lower index wins ties (matches lax.top_k)
        int i0 = 0; float v0 = acc[0];
#pragma unroll
        for (int e = 1; e < E_; ++e) if (acc[e] > v0) { v0 = acc[e]; i0 = e; }
        int i1 = -1; float v1 = -3.0e38f;
#pragma unroll
        for (int e = 0; e < E_; ++e) if (e != i0 && acc[e] > v1) { v1 = acc[e]; i1 = e; }
        float ex = expf(v1 - v0);
        float g0 = 1.f / (1.f + ex);
        float g1 = ex / (1.f + ex);
        choice_e[2 * n]     = i0;  choice_g[2 * n]     = g0;
        choice_e[2 * n + 1] = i1;  choice_g[2 * n + 1] = g1;
    }

    // fused y zeroing: 512 blocks x 12288 floats = N_*O_
    float4 z = {0.f, 0.f, 0.f, 0.f};
    float4* yb = (float4*)(y + (size_t)blockIdx.x * 12288);
#pragma unroll
    for (int i = 0; i < 12; ++i) yb[threadIdx.x + 256 * i] = z;
}

// ---------------- compact: per-expert lists + loss (1 block, ballot-aggregated)
__global__ __launch_bounds__(1024) void compact_kernel(
    const int* __restrict__ choice_e, const float* __restrict__ choice_g,
    int* __restrict__ counts, int* __restrict__ pair_token,
    float* __restrict__ pair_gate, float* __restrict__ out_loss)
{
    __shared__ int   s_cnt[E_];
    __shared__ float s_imp[E_];
    int t = threadIdx.x;
    int lane = t & 63;
    if (t < E_) s_cnt[t] = 0;
    __syncthreads();

#pragma unroll
    for (int it = 0; it < (2 * N_) / 1024; ++it) {
        int i = it * 1024 + t;
        int ce = choice_e[i];
        float gv = choice_g[i];
        unsigned long long mask[E_];
#pragma unroll
        for (int e = 0; e < E_; ++e) mask[e] = __ballot(ce == e);
        int b = 0;
        if (lane < E_) b = atomicAdd(&s_cnt[lane], __popcll(mask[lane]));
        int mybase = __shfl(b, ce, 64);
        unsigned long long mymask = mask[0];
#pragma unroll
        for (int e = 1; e < E_; ++e) if (ce == e) mymask = mask[e];
        int pos = mybase + __popcll(mymask & ((1ull << lane) - 1ull));
        pair_token[ce * N_ + pos] = i >> 1;
        pair_gate[ce * N_ + pos]  = gv;
    }
    __syncthreads();
    if (t < E_) counts[t] = s_cnt[t];

    // importance: 8 experts x 32 lanes strided sums, width-32 reduce
    if (t < 256) {
        int e = t >> 5, l = t & 31;
        int cnt = s_cnt[e];
        float p = 0.f;
        for (int i = l; i < cnt; i += 32) p += pair_gate[e * N_ + i];
#pragma unroll
        for (int off = 16; off > 0; off >>= 1) p += __shfl_down(p, off, 32);
        if (l == 0) s_imp[e] = p;
    }
    __syncthreads();
    if (t == 0) {
        float mi = 0.f, ml = 0.f, imp[E_], ld[E_];
#pragma unroll
        for (int i = 0; i < E_; ++i) {
            imp[i] = s_imp[i]; ld[i] = (float)s_cnt[i];
            mi += imp[i]; ml += ld[i];
        }
        mi /= (float)E_; ml /= (float)E_;
        float vi = 0.f, vl = 0.f;
#pragma unroll
        for (int i = 0; i < E_; ++i) {
            vi += (imp[i] - mi) * (imp[i] - mi);
            vl += (ld[i] - ml) * (ld[i] - ml);
        }
        vi /= (float)(E_ - 1); vl /= (float)(E_ - 1);
        *out_loss = 0.01f * (vi / (mi * mi + 1e-10f) + vl / (ml * ml + 1e-10f));
    }
}

// ---------------- grouped GEMM: 128x128x64, double-buffered async staging ----
// LDS layout (16B chunks): chunk(row,kch) = row*8 + (kch ^ (row&7)).
// Staging lane fetches global kch = (tid&7)^(row&7): coalesced 128B segments;
// MFMA reads land 2-per-bank-phase (free). Prefetch k+1 issued right after
// the barrier that consumed tile k -> loads fly under the MFMA phase.
#define BM 128
#define BN 128
#define BK 64

__global__ __launch_bounds__(256) void moe_gemm_kernel(
    const unsigned short* __restrict__ xb,   // [N_, D_] bf16
    const unsigned short* __restrict__ wb,   // [E_, O_, D_] bf16
    const float* __restrict__ expert_b,      // [E_, O_]
    const int* __restrict__ counts,
    const int* __restrict__ pair_token,
    const float* __restrict__ pair_gate,
    float* __restrict__ y)                   // [N_, O_]
{
    int e = blockIdx.z;
    int cnt = counts[e];
    int m0 = blockIdx.y * BM;
    if (m0 >= cnt) return;
    int n0 = blockIdx.x * BN;

    __shared__ __align__(16) unsigned short sA[2][BM * BK];   // 2 x 16 KB
    __shared__ __align__(16) unsigned short sB[2][BN * BK];   // 2 x 16 KB

    int tid  = threadIdx.x;
    int lane = tid & 63;
    int wid  = tid >> 6;
    int wm = wid & 1, wn = wid >> 1;
    int l16 = lane & 15;
    int quad = lane >> 4;

    // staging: rows r0+32s (s=0..3), fetched k-chunk kg constant across s
    int r0 = tid >> 3;                       // 0..31
    int kg = (tid & 7) ^ (r0 & 7);
    const unsigned short* gA[4];
    const unsigned short* gB[4];
#pragma unroll
    for (int s = 0; s < 4; ++s) {
        int row = r0 + 32 * s;
        int ar = m0 + row; if (ar >= cnt) ar = cnt - 1;
        gA[s] = xb + (size_t)pair_token[e * N_ + ar] * D_ + kg * 8;
        gB[s] = wb + ((size_t)e * O_ + n0 + row) * D_ + kg * 8;
    }
    char* lA[2] = { (char*)sA[0] + wid * 1024, (char*)sA[1] + wid * 1024 };
    char* lB[2] = { (char*)sB[0] + wid * 1024, (char*)sB[1] + wid * 1024 };

    f32x4 acc[4][4];
#pragma unroll
    for (int a = 0; a < 4; ++a)
#pragma unroll
        for (int b = 0; b < 4; ++b) acc[a][b] = (f32x4){0.f, 0.f, 0.f, 0.f};

    // prefetch tile 0 into buffer 0
#pragma unroll
    for (int s = 0; s < 4; ++s) {
        async16(gA[s], lA[0] + s * 4096);
        async16(gB[s], lB[0] + s * 4096);
    }

    int kb = 0;
    for (int k0 = 0; k0 < D_; k0 += BK, kb ^= 1) {
        __syncthreads();   // waits tile k0 arrival + all reads of buf kb^1 done
        int kn = k0 + BK;
        if (kn < D_) {
#pragma unroll
            for (int s = 0; s < 4; ++s) {
                async16(gA[s] + kn, lA[kb ^ 1] + s * 4096);
                async16(gB[s] + kn, lB[kb ^ 1] + s * 4096);
            }
        }
#pragma unroll
        for (int ks = 0; ks < 2; ++ks) {
            bf16x8 af[4], bfr[4];
#pragma unroll
            for (int mi = 0; mi < 4; ++mi) {
                int row = wm * 64 + mi * 16 + l16;
                int ch  = row * 8 + ((ks * 4 + quad) ^ (row & 7));
                af[mi] = *(const bf16x8*)&sA[kb][ch * 8];
            }
#pragma unroll
            for (int ni = 0; ni < 4; ++ni) {
                int row = wn * 64 + ni * 16 + l16;
                int ch  = row * 8 + ((ks * 4 + quad) ^ (row & 7));
                bfr[ni] = *(const bf16x8*)&sB[kb][ch * 8];
            }
#pragma unroll
            for (int mi = 0; mi < 4; ++mi)
#pragma unroll
                for (int ni = 0; ni < 4; ++ni)
                    acc[mi][ni] = __builtin_amdgcn_mfma_f32_16x16x32_bf16(
                        af[mi], bfr[ni], acc[mi][ni], 0, 0, 0);
        }
    }

    // epilogue: C/D map (16x16x32): col = lane&15, row = quad*4+reg  [verified]
    float bias[4];
#pragma unroll
    for (int ni = 0; ni < 4; ++ni)
        bias[ni] = expert_b[e * O_ + n0 + wn * 64 + ni * 16 + l16];
#pragma unroll
    for (int mi = 0; mi < 4; ++mi) {
        int rb = m0 + wm * 64 + mi * 16 + quad * 4;
#pragma unroll
        for (int reg = 0; reg < 4; ++reg) {
            int r = rb + reg;
            if (r < cnt) {
                int token  = pair_token[e * N_ + r];
                float gate = pair_gate[e * N_ + r];
#pragma unroll
                for (int ni = 0; ni < 4; ++ni) {
                    int o = n0 + wn * 64 + ni * 16 + l16;
                    atomicAdd(&y[(size_t)token * O_ + o],
                              gate * (acc[mi][ni][reg] + bias[ni]));
                }
            }
        }
    }
}

extern "C" void kernel_launch(void* const* d_in, const int* in_sizes, int n_in,
                              void* d_out, int out_size, void* d_ws, size_t ws_size,
                              hipStream_t stream) {
    const float* x        = (const float*)d_in[0];  // [4,512,768]
    const float* w_gate   = (const float*)d_in[1];  // [768,8]
    const float* expert_w = (const float*)d_in[2];  // [8,3072,768]
    const float* expert_b = (const float*)d_in[3];  // [8,3072]
    const float* static_w = (const float*)d_in[4];  // [3072,768]
    float* out = (float*)d_out;                     // y [N_,O_] then loss scalar

    char* ws = (char*)d_ws;
    int*   counts     = (int*)(ws + 0);
    int*   pair_token = (int*)(ws + 4096);
    float* pair_gate  = (float*)(ws + 4096 + 65536);
    int*   choice_e   = (int*)(ws + 4096 + 131072);
    float* choice_g   = (float*)(ws + 4096 + 131072 + 16384);
    unsigned short* xb = (unsigned short*)(ws + 4096 + 131072 + 32768);
    unsigned short* wb = (unsigned short*)(ws + 4096 + 131072 + 32768 + 3145728);

    prologue_kernel<<<512 + (E_ * O_ * D_ / 8) / 256, 256, 0, stream>>>(
        x, w_gate, expert_w, static_w, xb, wb, choice_e, choice_g, out);
    compact_kernel<<<1, 1024, 0, stream>>>(choice_e, choice_g, counts,
                                           pair_token, pair_gate, out + (size_t)N_ * O_);

    dim3 grid(O_ / BN, N_ / BM, E_);
    moe_gemm_kernel<<<grid, 256, 0, stream>>>(xb, wb, expert_b, counts,
                                              pair_token, pair_gate, out);
}

// Round 5
// 191.336 us; speedup vs baseline: 1.1250x; 1.1250x over previous
//
#include <hip/hip_runtime.h>
#include <hip/hip_bf16.h>
#include <stdint.h>

#define E_ 8
#define D_ 768
#define O_ 3072
#define N_ 2048   // B*S = 4*512

typedef __attribute__((ext_vector_type(8))) __bf16 bf16x8;
typedef __attribute__((ext_vector_type(4))) float f32x4;

// round-to-nearest-even fp32 -> bf16 bits
__device__ __forceinline__ unsigned short f2bf(float f) {
    union { float f; uint32_t u; } a; a.f = f;
    uint32_t u = a.u;
    uint32_t r = (u + 0x7fffu + ((u >> 16) & 1u)) >> 16;
    return (unsigned short)r;
}
__device__ __forceinline__ float bflo(uint32_t u) {
    union { uint32_t u; float f; } a; a.u = u << 16; return a.f;
}
__device__ __forceinline__ float bfhi(uint32_t u) {
    union { uint32_t u; float f; } a; a.u = u & 0xffff0000u; return a.f;
}

__device__ __forceinline__ void async16(const void* g, void* l) {
    __builtin_amdgcn_global_load_lds(
        (const __attribute__((address_space(1))) void*)g,
        (__attribute__((address_space(3))) void*)l, 16, 0, 0);
}

// ---------------- fused prologue ----------------
// blocks [0,512):       gating (1 wave/token) + x->bf16 cast
// blocks [512,512+9216): Wb[e] = bf16(expert_w[e] + static_w), 8 elem/thread
__global__ __launch_bounds__(256) void prologue_kernel(
    const float* __restrict__ x, const float* __restrict__ w_gate,
    const float* __restrict__ ew, const float* __restrict__ sw,
    unsigned short* __restrict__ xb, unsigned short* __restrict__ wb,
    int* __restrict__ choice_e, float* __restrict__ choice_g)
{
    if (blockIdx.x >= 512) {
        // ---- prep_w: one uint4 (8 bf16) store per thread ----
        int i = (blockIdx.x - 512) * 256 + threadIdx.x;   // 8-elem units
        int f = i * 8;
        const int od = O_ * D_;
        int e = f / od;
        int rem = f - e * od;
        float4 a0 = *(const float4*)(ew + f);
        float4 a1 = *(const float4*)(ew + f + 4);
        float4 b0 = *(const float4*)(sw + rem);
        float4 b1 = *(const float4*)(sw + rem + 4);
        union { ushort u[8]; uint4 v; } o;
        o.u[0] = f2bf(a0.x + b0.x); o.u[1] = f2bf(a0.y + b0.y);
        o.u[2] = f2bf(a0.z + b0.z); o.u[3] = f2bf(a0.w + b0.w);
        o.u[4] = f2bf(a1.x + b1.x); o.u[5] = f2bf(a1.y + b1.y);
        o.u[6] = f2bf(a1.z + b1.z); o.u[7] = f2bf(a1.w + b1.w);
        ((uint4*)wb)[i] = o.v;
        return;
    }

    // ---- gating ----
    int wid  = threadIdx.x >> 6;
    int lane = threadIdx.x & 63;
    int n = blockIdx.x * 4 + wid;
    const float* xr = x + (size_t)n * D_;

    float acc[E_];
#pragma unroll
    for (int e = 0; e < E_; ++e) acc[e] = 0.f;

    for (int c = 0; c < D_ / 64; ++c) {
        int d = c * 64 + lane;
        float xv = xr[d];
        xb[(size_t)n * D_ + d] = f2bf(xv);          // fused cast
        const float* wg = w_gate + (size_t)d * E_;
        float4 w0 = *(const float4*)(wg);
        float4 w1 = *(const float4*)(wg + 4);
        acc[0] += xv * w0.x; acc[1] += xv * w0.y;
        acc[2] += xv * w0.z; acc[3] += xv * w0.w;
        acc[4] += xv * w1.x; acc[5] += xv * w1.y;
        acc[6] += xv * w1.z; acc[7] += xv * w1.w;
    }
#pragma unroll
    for (int e = 0; e < E_; ++e) {
        float v = acc[e];
        for (int off = 32; off > 0; off >>= 1) v += __shfl_xor(v, off, 64);
        acc[e] = v;
    }
    if (lane == 0) {
        // top-2, lower index wins ties (matches lax.top_k)
        int i0 = 0; float v0 = acc[0];
#pragma unroll
        for (int e = 1; e < E_; ++e) if (acc[e] > v0) { v0 = acc[e]; i0 = e; }
        int i1 = -1; float v1 = -3.0e38f;
#pragma unroll
        for (int e = 0; e < E_; ++e) if (e != i0 && acc[e] > v1) { v1 = acc[e]; i1 = e; }
        float ex = expf(v1 - v0);
        float g0 = 1.f / (1.f + ex);
        float g1 = ex / (1.f + ex);
        choice_e[2 * n]     = i0;  choice_g[2 * n]     = g0;
        choice_e[2 * n + 1] = i1;  choice_g[2 * n + 1] = g1;
    }
}

// ---------------- compact: per-expert pair lists + loss (1 block) ----------
// pair list entries are PAIR IDS: pid = 2*token + slot  (dense, unique)
__global__ __launch_bounds__(1024) void compact_kernel(
    const int* __restrict__ choice_e, const float* __restrict__ choice_g,
    int* __restrict__ counts, int* __restrict__ pair_id,
    float* __restrict__ pair_gate, float* __restrict__ out_loss)
{
    __shared__ int   s_cnt[E_];
    __shared__ float s_imp[E_];
    int t = threadIdx.x;
    int lane = t & 63;
    if (t < E_) s_cnt[t] = 0;
    __syncthreads();

#pragma unroll
    for (int it = 0; it < (2 * N_) / 1024; ++it) {
        int i = it * 1024 + t;
        int ce = choice_e[i];
        float gv = choice_g[i];
        unsigned long long mask[E_];
#pragma unroll
        for (int e = 0; e < E_; ++e) mask[e] = __ballot(ce == e);
        int b = 0;
        if (lane < E_) b = atomicAdd(&s_cnt[lane], __popcll(mask[lane]));
        int mybase = __shfl(b, ce, 64);
        unsigned long long mymask = mask[0];
#pragma unroll
        for (int e = 1; e < E_; ++e) if (ce == e) mymask = mask[e];
        int pos = mybase + __popcll(mymask & ((1ull << lane) - 1ull));
        pair_id[ce * N_ + pos]   = i;          // pid = 2*token + slot
        pair_gate[ce * N_ + pos] = gv;
    }
    __syncthreads();
    if (t < E_) counts[t] = s_cnt[t];

    // importance: 8 experts x 32 lanes strided sums, width-32 reduce
    if (t < 256) {
        int e = t >> 5, l = t & 31;
        int cnt = s_cnt[e];
        float p = 0.f;
        for (int i = l; i < cnt; i += 32) p += pair_gate[e * N_ + i];
#pragma unroll
        for (int off = 16; off > 0; off >>= 1) p += __shfl_down(p, off, 32);
        if (l == 0) s_imp[e] = p;
    }
    __syncthreads();
    if (t == 0) {
        float mi = 0.f, ml = 0.f, imp[E_], ld[E_];
#pragma unroll
        for (int i = 0; i < E_; ++i) {
            imp[i] = s_imp[i]; ld[i] = (float)s_cnt[i];
            mi += imp[i]; ml += ld[i];
        }
        mi /= (float)E_; ml /= (float)E_;
        float vi = 0.f, vl = 0.f;
#pragma unroll
        for (int i = 0; i < E_; ++i) {
            vi += (imp[i] - mi) * (imp[i] - mi);
            vl += (ld[i] - ml) * (ld[i] - ml);
        }
        vi /= (float)(E_ - 1); vl /= (float)(E_ - 1);
        *out_loss = 0.01f * (vi / (mi * mi + 1e-10f) + vl / (ml * ml + 1e-10f));
    }
}

// ---------------- grouped GEMM: 128x128x64, double-buffered async staging ----
// Epilogue: PLAIN bf16 stores to part[pid][o] (no atomics; every element of
// part is written exactly once since pids are dense in [0, 2N)).
#define BM 128
#define BN 128
#define BK 64

__global__ __launch_bounds__(256) void moe_gemm_kernel(
    const unsigned short* __restrict__ xb,   // [N_, D_] bf16
    const unsigned short* __restrict__ wb,   // [E_, O_, D_] bf16
    const float* __restrict__ expert_b,      // [E_, O_]
    const int* __restrict__ counts,
    const int* __restrict__ pair_id,         // pid = 2*token + slot
    const float* __restrict__ pair_gate,
    unsigned short* __restrict__ part)       // [2*N_, O_] bf16
{
    int e = blockIdx.z;
    int cnt = counts[e];
    int m0 = blockIdx.y * BM;
    if (m0 >= cnt) return;
    int n0 = blockIdx.x * BN;

    __shared__ __align__(16) unsigned short sA[2][BM * BK];   // 2 x 16 KB
    __shared__ __align__(16) unsigned short sB[2][BN * BK];   // 2 x 16 KB

    int tid  = threadIdx.x;
    int lane = tid & 63;
    int wid  = tid >> 6;
    int wm = wid & 1, wn = wid >> 1;
    int l16 = lane & 15;
    int quad = lane >> 4;

    // staging: rows r0+32s (s=0..3), fetched k-chunk kg constant across s
    int r0 = tid >> 3;                       // 0..31
    int kg = (tid & 7) ^ (r0 & 7);
    const unsigned short* gA[4];
    const unsigned short* gB[4];
#pragma unroll
    for (int s = 0; s < 4; ++s) {
        int row = r0 + 32 * s;
        int ar = m0 + row; if (ar >= cnt) ar = cnt - 1;
        gA[s] = xb + (size_t)(pair_id[e * N_ + ar] >> 1) * D_ + kg * 8;
        gB[s] = wb + ((size_t)e * O_ + n0 + row) * D_ + kg * 8;
    }
    char* lA[2] = { (char*)sA[0] + wid * 1024, (char*)sA[1] + wid * 1024 };
    char* lB[2] = { (char*)sB[0] + wid * 1024, (char*)sB[1] + wid * 1024 };

    f32x4 acc[4][4];
#pragma unroll
    for (int a = 0; a < 4; ++a)
#pragma unroll
        for (int b = 0; b < 4; ++b) acc[a][b] = (f32x4){0.f, 0.f, 0.f, 0.f};

    // prefetch tile 0 into buffer 0
#pragma unroll
    for (int s = 0; s < 4; ++s) {
        async16(gA[s], lA[0] + s * 4096);
        async16(gB[s], lB[0] + s * 4096);
    }

    int kb = 0;
    for (int k0 = 0; k0 < D_; k0 += BK, kb ^= 1) {
        __syncthreads();   // waits tile k0 arrival + all reads of buf kb^1 done
        int kn = k0 + BK;
        if (kn < D_) {
#pragma unroll
            for (int s = 0; s < 4; ++s) {
                async16(gA[s] + kn, lA[kb ^ 1] + s * 4096);
                async16(gB[s] + kn, lB[kb ^ 1] + s * 4096);
            }
        }
#pragma unroll
        for (int ks = 0; ks < 2; ++ks) {
            bf16x8 af[4], bfr[4];
#pragma unroll
            for (int mi = 0; mi < 4; ++mi) {
                int row = wm * 64 + mi * 16 + l16;
                int ch  = row * 8 + ((ks * 4 + quad) ^ (row & 7));
                af[mi] = *(const bf16x8*)&sA[kb][ch * 8];
            }
#pragma unroll
            for (int ni = 0; ni < 4; ++ni) {
                int row = wn * 64 + ni * 16 + l16;
                int ch  = row * 8 + ((ks * 4 + quad) ^ (row & 7));
                bfr[ni] = *(const bf16x8*)&sB[kb][ch * 8];
            }
#pragma unroll
            for (int mi = 0; mi < 4; ++mi)
#pragma unroll
                for (int ni = 0; ni < 4; ++ni)
                    acc[mi][ni] = __builtin_amdgcn_mfma_f32_16x16x32_bf16(
                        af[mi], bfr[ni], acc[mi][ni], 0, 0, 0);
        }
    }

    // epilogue: C/D map (16x16x32): col = lane&15, row = quad*4+reg  [verified]
    float bias[4];
#pragma unroll
    for (int ni = 0; ni < 4; ++ni)
        bias[ni] = expert_b[e * O_ + n0 + wn * 64 + ni * 16 + l16];
#pragma unroll
    for (int mi = 0; mi < 4; ++mi) {
        int rb = m0 + wm * 64 + mi * 16 + quad * 4;
#pragma unroll
        for (int reg = 0; reg < 4; ++reg) {
            int r = rb + reg;
            if (r < cnt) {
                int pid    = pair_id[e * N_ + r];
                float gate = pair_gate[e * N_ + r];
#pragma unroll
                for (int ni = 0; ni < 4; ++ni) {
                    int o = n0 + wn * 64 + ni * 16 + l16;
                    part[(size_t)pid * O_ + o] =
                        f2bf(gate * (acc[mi][ni][reg] + bias[ni]));
                }
            }
        }
    }
}

// ---------------- reduce: y[n] = part[2n] + part[2n+1] ----------------
__global__ __launch_bounds__(256) void reduce_kernel(
    const unsigned short* __restrict__ part, float* __restrict__ y)
{
    int i = blockIdx.x * 256 + threadIdx.x;     // 8-col unit
    int n = i / (O_ / 8);
    int c = (i - n * (O_ / 8)) * 8;
    const uint4 p0 = *(const uint4*)(part + (size_t)(2 * n) * O_ + c);
    const uint4 p1 = *(const uint4*)(part + (size_t)(2 * n + 1) * O_ + c);
    float4 o0, o1;
    o0.x = bflo(p0.x) + bflo(p1.x); o0.y = bfhi(p0.x) + bfhi(p1.x);
    o0.z = bflo(p0.y) + bflo(p1.y); o0.w = bfhi(p0.y) + bfhi(p1.y);
    o1.x = bflo(p0.z) + bflo(p1.z); o1.y = bfhi(p0.z) + bfhi(p1.z);
    o1.z = bflo(p0.w) + bflo(p1.w); o1.w = bfhi(p0.w) + bfhi(p1.w);
    float* yp = y + (size_t)n * O_ + c;
    *(float4*)(yp)     = o0;
    *(float4*)(yp + 4) = o1;
}

extern "C" void kernel_launch(void* const* d_in, const int* in_sizes, int n_in,
                              void* d_out, int out_size, void* d_ws, size_t ws_size,
                              hipStream_t stream) {
    const float* x        = (const float*)d_in[0];  // [4,512,768]
    const float* w_gate   = (const float*)d_in[1];  // [768,8]
    const float* expert_w = (const float*)d_in[2];  // [8,3072,768]
    const float* expert_b = (const float*)d_in[3];  // [8,3072]
    const float* static_w = (const float*)d_in[4];  // [3072,768]
    float* out = (float*)d_out;                     // y [N_,O_] then loss scalar

    char* ws = (char*)d_ws;
    int*   counts    = (int*)(ws + 0);
    int*   pair_id   = (int*)(ws + 4096);
    float* pair_gate = (float*)(ws + 69632);
    int*   choice_e  = (int*)(ws + 135168);
    float* choice_g  = (float*)(ws + 151552);
    unsigned short* xb   = (unsigned short*)(ws + 167936);
    unsigned short* wb   = (unsigned short*)(ws + 3313664);
    unsigned short* part = (unsigned short*)(ws + 41062400);  // [2N, O] bf16, 24 MB

    prologue_kernel<<<512 + (E_ * O_ * D_ / 8) / 256, 256, 0, stream>>>(
        x, w_gate, expert_w, static_w, xb, wb, choice_e, choice_g);
    compact_kernel<<<1, 1024, 0, stream>>>(choice_e, choice_g, counts,
                                           pair_id, pair_gate, out + (size_t)N_ * O_);

    dim3 grid(O_ / BN, N_ / BM, E_);
    moe_gemm_kernel<<<grid, 256, 0, stream>>>(xb, wb, expert_b, counts,
                                              pair_id, pair_gate, part);

    reduce_kernel<<<(N_ * O_ / 8) / 256, 256, 0, stream>>>(part, out);
}